// Round 6
// baseline (795.395 us; speedup 1.0000x reference)
//
#include <hip/hip_runtime.h>
#include <hip/hip_bf16.h>

typedef unsigned short u16;
typedef unsigned int   u32;
typedef unsigned long long u64;

using short8 = __attribute__((ext_vector_type(8))) short;
using f32x4  = __attribute__((ext_vector_type(4))) float;
using u16x8  = __attribute__((ext_vector_type(8))) unsigned short;

#define AS_GLOBAL __attribute__((address_space(1)))
#define AS_LDS    __attribute__((address_space(3)))

// ---- bf16 helpers (manual RNE) ----
__device__ __forceinline__ u16 f2b(float x){
  u32 u = __float_as_uint(x);
  u32 r = (u + 0x7FFFu + ((u >> 16) & 1u)) >> 16;
  return (u16)r;
}
__device__ __forceinline__ float b2f(u16 h){ return __uint_as_float(((u32)h) << 16); }

__device__ __forceinline__ void gload16(u16* l, const u16* g){
  __builtin_amdgcn_global_load_lds((const AS_GLOBAL u32*)g, (AS_LDS u32*)l, 16, 0, 0);
}

__device__ __forceinline__ u64 umin64(u64 a, u64 b){ return a < b ? a : b; }

__device__ __forceinline__ u64 shfl_xor_u64(u64 v, int m){
  u32 lo = __shfl_xor((u32)v, m, 64);
  u32 hi = __shfl_xor((u32)(v >> 32), m, 64);
  return ((u64)hi << 32) | lo;
}

// ---- prep kernels ----
__global__ void k_cvt(const float* __restrict__ w, u16* __restrict__ d, int n){
  int i = blockIdx.x * 256 + threadIdx.x;
  if (i < n) d[i] = f2b(w[i]);
}

__global__ void k_cnorm(const float* __restrict__ emb, float* __restrict__ cnorm){
  int v = blockIdx.x, lane = threadIdx.x;
  const float* r = emb + (size_t)v * 512;
  float s = 0.f;
  #pragma unroll
  for (int i = 0; i < 8; ++i){ float x = r[lane + i * 64]; s += x * x; }
  #pragma unroll
  for (int off = 32; off; off >>= 1) s += __shfl_down(s, off, 64);
  if (lane == 0) cnorm[v] = s;
}

// ---- transpose+convert: src f32 [256 b][512 r][256 c] -> d bf16 [b][c][r] ----
__global__ void k_tcvt(const float* __restrict__ src, u16* __restrict__ d){
  __shared__ float t[64][65];
  const int bid = blockIdx.x;
  const int b  = bid >> 5;
  const int rb = (bid >> 2) & 7;
  const int cb = bid & 3;
  const float* s = src + ((size_t)b * 512 + (size_t)rb * 64) * 256 + cb * 64;
  const int tid = threadIdx.x;
  #pragma unroll
  for (int j = 0; j < 4; ++j){
    int fl = j * 256 + tid;
    int r = fl >> 4, c4 = (fl & 15) * 4;
    float4 v = *(const float4*)(s + (size_t)r * 256 + c4);
    t[r][c4 + 0] = v.x; t[r][c4 + 1] = v.y; t[r][c4 + 2] = v.z; t[r][c4 + 3] = v.w;
  }
  __syncthreads();
  u16* o = d + ((size_t)b * 256 + (size_t)cb * 64) * 512 + rb * 64;
  #pragma unroll
  for (int j = 0; j < 2; ++j){
    int fl = j * 256 + tid;
    int c = fl >> 3, r8 = (fl & 7) * 8;
    u16x8 hv;
    #pragma unroll
    for (int i = 0; i < 8; ++i) hv[i] = f2b(t[r8 + i][c]);
    *(u16x8*)(o + (size_t)c * 512 + r8) = hv;
  }
}

// ---- z_q gather ----
__global__ void k_zq(const u64* __restrict__ keys, const float* __restrict__ emb, float* __restrict__ zq){
  int sidx = blockIdx.x * 64 + threadIdx.x;
  int b = sidx >> 8, s = sidx & 255;
  int v = (int)(u32)keys[sidx];
  const float4* er = (const float4*)(emb + (size_t)v * 512);
  float* o = zq + (size_t)b * 512 * 256 + s;
  #pragma unroll 4
  for (int e4 = 0; e4 < 128; ++e4){
    float4 vv = er[e4];
    o[(size_t)(e4 * 4 + 0) * 256] = vv.x;
    o[(size_t)(e4 * 4 + 1) * 256] = vv.y;
    o[(size_t)(e4 * 4 + 2) * 256] = vv.z;
    o[(size_t)(e4 * 4 + 3) * 256] = vv.w;
  }
}

// ---- small GEMM (proven 128x128 2-phase): GEMM1 & GEMM3 ----
template<int MODE>
__global__ __launch_bounds__(256, 4) void k_gemm(
    const u16* __restrict__ Ah,
    const u16* __restrict__ Bh,
    const u64* __restrict__ gkeys,
    const float* __restrict__ bias,
    float* __restrict__ Cout,
    int M, int mtbits)
{
  constexpr int K = 512;
  __shared__ __align__(16) u16 sA[128 * 64];
  __shared__ __align__(16) u16 sB[128 * 64];

  const int tid  = threadIdx.x;
  const int lane = tid & 63;
  const int wid  = tid >> 6;
  const int wm = wid >> 1, wn = wid & 1;

  const int nwg = gridDim.x;
  const int chunk = nwg >> 3;
  const int pb = blockIdx.x;
  const int bid = (pb & 7) * chunk + (pb >> 3);

  const int mt = bid & ((1 << mtbits) - 1);
  const int nt = (bid >> mtbits) & 1;
  const int b  = bid >> (mtbits + 1);
  const int m0 = mt * 128;
  const int n0 = nt * 128;
  const int bbase = b * 256;

  const u16* ga[4];
  const u16* gb[4];
  int ldso[4];
  #pragma unroll
  for (int i = 0; i < 4; ++i){
    int e = i * 256 + tid;
    int r = e >> 3;
    int sl = (e & 7) ^ (r & 7);
    ldso[i] = e * 8;
    ga[i] = Ah + (size_t)(m0 + r) * K + sl * 8;
    size_t brow;
    if (MODE == 2) brow = (size_t)(u32)gkeys[bbase + n0 + r];
    else           brow = (size_t)(bbase + n0 + r);
    gb[i] = Bh + brow * K + sl * 8;
  }

  const f32x4 zero4 = {0.f, 0.f, 0.f, 0.f};
  f32x4 acc[4][4];
  #pragma unroll
  for (int i = 0; i < 4; ++i)
    #pragma unroll
    for (int j = 0; j < 4; ++j) acc[i][j] = zero4;

  int aoff[2][4], boff[2][4];
  #pragma unroll
  for (int ks = 0; ks < 2; ++ks)
    #pragma unroll
    for (int f = 0; f < 4; ++f){
      int rA = wm * 64 + f * 16 + (lane & 15);
      aoff[ks][f] = rA * 64 + (((ks * 4 + (lane >> 4)) ^ (rA & 7)) * 8);
      int rB = wn * 64 + f * 16 + (lane & 15);
      boff[ks][f] = rB * 64 + (((ks * 4 + (lane >> 4)) ^ (rB & 7)) * 8);
    }

  for (int kt = 0; kt < 8; ++kt){
    const int k0 = kt * 64;
    #pragma unroll
    for (int i = 0; i < 4; ++i){
      gload16(&sA[ldso[i]], ga[i] + k0);
      gload16(&sB[ldso[i]], gb[i] + k0);
    }
    __syncthreads();
    #pragma unroll
    for (int ks = 0; ks < 2; ++ks){
      short8 ah[4], bh[4];
      #pragma unroll
      for (int f = 0; f < 4; ++f){
        ah[f] = *(const short8*)&sA[aoff[ks][f]];
        bh[f] = *(const short8*)&sB[boff[ks][f]];
      }
      #pragma unroll
      for (int fm = 0; fm < 4; ++fm)
        #pragma unroll
        for (int fn = 0; fn < 4; ++fn)
          acc[fm][fn] = __builtin_amdgcn_mfma_f32_16x16x32_bf16(ah[fm], bh[fn], acc[fm][fn], 0, 0, 0);
    }
    __syncthreads();
  }

  const int row0 = m0 + wm * 64;
  const int col  = n0 + wn * 64 + (lane & 15);
  float* Cb = Cout + (size_t)b * M * 256;
  #pragma unroll
  for (int fm = 0; fm < 4; ++fm){
    #pragma unroll
    for (int j = 0; j < 4; ++j){
      int row = row0 + fm * 16 + (lane >> 4) * 4 + j;
      float bi = bias[row];
      #pragma unroll
      for (int fn = 0; fn < 4; ++fn)
        Cb[(size_t)row * 256 + col + fn * 16] = acc[fm][fn][j] + bi;
    }
  }
}

// ---- GEMM2: 4-wave block, B panel in AGPRs via inline-asm MFMA ----
// One block per b (256 blocks, 256 thr, 1/CU, 1 wave/SIMD). BM=128, BN=256.
// Per-wave output 128x64 (wn = wave id). acc[8][4] f32x4 in AGPR ("+a"),
// bf[8][2][4] short8 (whole per-wave B panel, 256 regs) in AGPR ("a" input).
// Arch VGPR ~120 + 384 AGPR < 512 unified @ 1 wave/SIMD.
// LDS: quad-buffered A tiles (4 x 16KB, slot^row&7 swizzle) + cn 16KB.
// Tile stream tau=0..255 (mt 0..31 x kt 0..7): stage A(tau+2) [4 gloads/thr],
// counted vmcnt(8) (drains exactly A(tau)), barrier, 16 ds_read (both ks,
// issued up-front so ks1 latency hides under ks0 MFMAs), 64 asm MFMA.
// bf loads retired from vmcnt scoreboard by the __syncthreads before staging.
// s_nop pair before epilogue accvgpr reads (asm MFMA is opaque to hazard pass).
#define MFMA_AB(d, s0, s1) asm volatile("v_mfma_f32_16x16x32_bf16 %0, %1, %2, %0" : "+a"(d) : "v"(s0), "a"(s1))

__global__ __launch_bounds__(256, 1) void k_gemm2(
    const u16* __restrict__ Ah,      // emb_b [4096][512]
    const u16* __restrict__ Bh,      // zb [65536][512]
    const float* __restrict__ cnorm,
    u64* __restrict__ okeys)
{
  __shared__ __align__(16) u16 lds[40960];  // 4 A-bufs (4x8192 u16) + cn (8192 u16)

  const int tid  = threadIdx.x;
  const int lane = tid & 63;
  const int wn   = tid >> 6;          // 4 waves = 4 col-groups of 64 tokens
  const int b    = blockIdx.x;
  const int bbase = b * 256;

  // ---- B panel -> AGPR-bound registers (loaded once, coalesced-ish, L3-warm) ----
  short8 bf[8][2][4];
  {
    const u16* bp = Bh + (size_t)(bbase + wn * 64 + (lane & 15)) * 512 + (lane >> 4) * 8;
    #pragma unroll
    for (int kt = 0; kt < 8; ++kt)
      #pragma unroll
      for (int ks = 0; ks < 2; ++ks)
        #pragma unroll
        for (int f = 0; f < 4; ++f)
          bf[kt][ks][f] = *(const short8*)(bp + f * 8192 + kt * 64 + ks * 32);
  }

  // cnorm -> LDS
  float* cn = (float*)&lds[32768];
  {
    const float4* c4 = (const float4*)cnorm;
    #pragma unroll
    for (int i = 0; i < 4; ++i)
      ((float4*)cn)[tid + i * 256] = c4[tid + i * 256];
  }
  // barrier also drains vmcnt->0: bf loads retire from the scoreboard here,
  // so the loop's counted vmcnt(8) tracks ONLY staging gloads.
  __syncthreads();

  // ---- A staging descriptors (4 x 16B per thread per 128x64 tile) ----
  const u16* ga[4];
  #pragma unroll
  for (int i = 0; i < 4; ++i){
    int e = i * 256 + tid;          // 0..1023 16B-slots
    int r = e >> 3;                 // tile row 0..127
    int sl = (e & 7) ^ (r & 7);     // pre-unswizzled source slot
    ga[i] = Ah + (size_t)r * 512 + sl * 8;
  }
  const int dofs = tid * 8;

#define STG_A(tp) { const int _o = ((tp) >> 3) * 65536 + ((tp) & 7) * 64; \
    const int _d = ((tp) & 3) * 8192; \
    _Pragma("unroll") for (int i_ = 0; i_ < 4; ++i_) \
      gload16(&lds[_d + i_ * 2048 + dofs], ga[i_] + _o); }
#define VM8 asm volatile("s_waitcnt vmcnt(8)" ::: "memory");
#define VM4 asm volatile("s_waitcnt vmcnt(4)" ::: "memory");
#define VM0 asm volatile("s_waitcnt vmcnt(0)" ::: "memory");

  // A-frag ds_read bases; rows f*16+(lane&15), (row&7)==(lane&7)
  int aoffK[2];
  #pragma unroll
  for (int ks = 0; ks < 2; ++ks)
    aoffK[ks] = (lane & 15) * 64 + (((ks * 4 + (lane >> 4)) ^ (lane & 7)) * 8);

  const f32x4 zero4 = {0.f, 0.f, 0.f, 0.f};
  f32x4 acc[8][4];
  #pragma unroll
  for (int i = 0; i < 8; ++i)
    #pragma unroll
    for (int j = 0; j < 4; ++j) acc[i][j] = zero4;

  u64 best[4];
  #pragma unroll
  for (int i = 0; i < 4; ++i) best[i] = ~0ull;

  // prologue: stage tiles 0,1 (8 outstanding)
  STG_A(0)
  STG_A(1)

  for (int mt = 0; mt < 32; ++mt){
    #pragma unroll
    for (int kt = 0; kt < 8; ++kt){
      const int tau = mt * 8 + kt;
      // stage A(tau+2) then counted wait (drains exactly A(tau)); tail drains
      if (kt < 6){ STG_A(tau + 2) VM8 }
      else if (kt == 6){ if (mt < 31){ STG_A(tau + 2) VM8 } else { VM4 } }
      else            { if (mt < 31){ STG_A(tau + 2) VM8 } else { VM0 } }
      __builtin_amdgcn_s_barrier();
      __builtin_amdgcn_sched_barrier(0);

      const int rbuf = (tau & 3) * 8192;
      // issue ALL 16 ds_reads up-front: ks1 latency hides under ks0 MFMAs
      short8 ah0[8], ah1[8];
      #pragma unroll
      for (int f = 0; f < 8; ++f) ah0[f] = *(const short8*)&lds[rbuf + aoffK[0] + f * 1024];
      #pragma unroll
      for (int f = 0; f < 8; ++f) ah1[f] = *(const short8*)&lds[rbuf + aoffK[1] + f * 1024];
      __builtin_amdgcn_s_setprio(1);
      #pragma unroll
      for (int fm = 0; fm < 8; ++fm)
        #pragma unroll
        for (int f = 0; f < 4; ++f)
          MFMA_AB(acc[fm][f], ah0[fm], bf[kt][0][f]);
      #pragma unroll
      for (int fm = 0; fm < 8; ++fm)
        #pragma unroll
        for (int f = 0; f < 4; ++f)
          MFMA_AB(acc[fm][f], ah1[fm], bf[kt][1][f]);
      __builtin_amdgcn_s_setprio(0);
    }

    // MFMA(asm)->VALU read hazard gap (hazard pass can't see inside asm)
    asm volatile("s_nop 7\n\ts_nop 7\n\ts_nop 7" :::);

    // per-mt epilogue: fold scores into running best
    #pragma unroll
    for (int fn = 0; fn < 4; ++fn){
      #pragma unroll
      for (int fm = 0; fm < 8; ++fm){
        #pragma unroll
        for (int j = 0; j < 4; ++j){
          int v = mt * 128 + fm * 16 + (lane >> 4) * 4 + j;
          float sc = cn[v] - 2.0f * acc[fm][fn][j];
          u32 o = __float_as_uint(sc);
          o = (o & 0x80000000u) ? ~o : (o | 0x80000000u);
          best[fn] = umin64(best[fn], ((u64)o << 32) | (u32)v);
        }
      }
    }
    #pragma unroll
    for (int i = 0; i < 8; ++i)
      #pragma unroll
      for (int j = 0; j < 4; ++j) acc[i][j] = zero4;
  }

  // per-wave reduce over the 4 lane-rows sharing each token column; store
  #pragma unroll
  for (int fn = 0; fn < 4; ++fn){
    best[fn] = umin64(best[fn], shfl_xor_u64(best[fn], 16));
    best[fn] = umin64(best[fn], shfl_xor_u64(best[fn], 32));
  }
  if (lane < 16){
    #pragma unroll
    for (int fn = 0; fn < 4; ++fn)
      okeys[bbase + wn * 64 + fn * 16 + (lane & 15)] = best[fn];
  }

#undef STG_A
#undef VM8
#undef VM4
#undef VM0
}

extern "C" void kernel_launch(void* const* d_in, const int* in_sizes, int n_in,
                              void* d_out, int out_size, void* d_ws, size_t ws_size,
                              hipStream_t stream){
  const float* x      = (const float*)d_in[0];
  const float* pre_w  = (const float*)d_in[1];
  const float* pre_b  = (const float*)d_in[2];
  const float* emb    = (const float*)d_in[3];
  const float* post_w = (const float*)d_in[4];
  const float* post_b = (const float*)d_in[5];

  float* z_out   = (float*)d_out;              // [256][512][256]
  float* zq_out  = z_out + 33554432;           // [256][512][256]
  float* rec_out = z_out + 67108864;           // [256][512][256]

  char* w = (char*)d_ws;
  u16* prew_b  = (u16*)(w);                    // 512KB
  u16* postw_b = (u16*)(w + 524288);           // 512KB
  u16* emb_b   = (u16*)(w + 1048576);          // 4MB
  float* cnorm = (float*)(w + 5242880);        // 16KB
  u64* keys    = (u64*)(w + 5259264);          // 512KB
  u16* xb      = (u16*)(w + 5783552);          // 64MB [65536][512] bf16
  u16* zb = xb;                                // z^T bf16 aliases xb (disjoint lifetime)

  k_cvt  <<<1024, 256, 0, stream>>>(pre_w, prew_b, 262144);
  k_cvt  <<<1024, 256, 0, stream>>>(post_w, postw_b, 262144);
  k_cvt  <<<8192, 256, 0, stream>>>(emb, emb_b, 2097152);
  k_cnorm<<<4096, 64, 0, stream>>>(emb, cnorm);

  // x [b][c][s] -> xb [b][s][c]
  k_tcvt<<<8192, 256, 0, stream>>>(x, xb);

  // GEMM1: z = pre_w * x + pre_b
  k_gemm<0><<<256 * 2 * 4, 256, 0, stream>>>(prew_b, xb,
      nullptr, pre_b, z_out, 512, 2);

  // z [b][e][s] -> zb [b][s][e]
  k_tcvt<<<8192, 256, 0, stream>>>(z_out, zb);

  // GEMM2: per-batch scores + argmin -> keys (B panel in AGPRs)
  k_gemm2<<<256, 256, 0, stream>>>(emb_b, zb, cnorm, keys);

  // z_q gather (exact f32)
  k_zq<<<1024, 64, 0, stream>>>(keys, emb, zq_out);

  // GEMM3: rec = post_w * z_q + post_b  (B staged by gathering emb_b rows via tokens)
  k_gemm<2><<<256 * 2 * 4, 256, 0, stream>>>(postw_b, emb_b,
      keys, post_b, rec_out, 512, 2);
}

// Round 7
// 544.060 us; speedup vs baseline: 1.4620x; 1.4620x over previous
//
#include <hip/hip_runtime.h>
#include <hip/hip_bf16.h>

typedef unsigned short u16;
typedef unsigned int   u32;
typedef unsigned long long u64;

using short8 = __attribute__((ext_vector_type(8))) short;
using f32x4  = __attribute__((ext_vector_type(4))) float;
using u16x4  = __attribute__((ext_vector_type(4))) unsigned short;
using u16x8  = __attribute__((ext_vector_type(8))) unsigned short;

#define AS_GLOBAL __attribute__((address_space(1)))
#define AS_LDS    __attribute__((address_space(3)))

// ---- bf16 helpers (manual RNE) ----
__device__ __forceinline__ u16 f2b(float x){
  u32 u = __float_as_uint(x);
  u32 r = (u + 0x7FFFu + ((u >> 16) & 1u)) >> 16;
  return (u16)r;
}
__device__ __forceinline__ float b2f(u16 h){ return __uint_as_float(((u32)h) << 16); }

__device__ __forceinline__ void gload16(u16* l, const u16* g){
  __builtin_amdgcn_global_load_lds((const AS_GLOBAL u32*)g, (AS_LDS u32*)l, 16, 0, 0);
}

__device__ __forceinline__ u64 umin64(u64 a, u64 b){ return a < b ? a : b; }

__device__ __forceinline__ u64 shfl_xor_u64(u64 v, int m){
  u32 lo = __shfl_xor((u32)v, m, 64);
  u32 hi = __shfl_xor((u32)(v >> 32), m, 64);
  return ((u64)hi << 32) | lo;
}

// ---- prep kernels ----
__global__ void k_cvt(const float* __restrict__ w, u16* __restrict__ d, int n){
  int i = blockIdx.x * 256 + threadIdx.x;
  if (i < n) d[i] = f2b(w[i]);
}

__global__ void k_cnorm(const float* __restrict__ emb, float* __restrict__ cnorm){
  int v = blockIdx.x, lane = threadIdx.x;
  const float* r = emb + (size_t)v * 512;
  float s = 0.f;
  #pragma unroll
  for (int i = 0; i < 8; ++i){ float x = r[lane + i * 64]; s += x * x; }
  #pragma unroll
  for (int off = 32; off; off >>= 1) s += __shfl_down(s, off, 64);
  if (lane == 0) cnorm[v] = s;
}

// ---- transpose+convert: src f32 [256 b][512 r][256 c] -> d bf16 [b][c][r] ----
__global__ void k_tcvt(const float* __restrict__ src, u16* __restrict__ d){
  __shared__ float t[64][65];
  const int bid = blockIdx.x;
  const int b  = bid >> 5;
  const int rb = (bid >> 2) & 7;
  const int cb = bid & 3;
  const float* s = src + ((size_t)b * 512 + (size_t)rb * 64) * 256 + cb * 64;
  const int tid = threadIdx.x;
  #pragma unroll
  for (int j = 0; j < 4; ++j){
    int fl = j * 256 + tid;
    int r = fl >> 4, c4 = (fl & 15) * 4;
    float4 v = *(const float4*)(s + (size_t)r * 256 + c4);
    t[r][c4 + 0] = v.x; t[r][c4 + 1] = v.y; t[r][c4 + 2] = v.z; t[r][c4 + 3] = v.w;
  }
  __syncthreads();
  u16* o = d + ((size_t)b * 256 + (size_t)cb * 64) * 512 + rb * 64;
  #pragma unroll
  for (int j = 0; j < 2; ++j){
    int fl = j * 256 + tid;
    int c = fl >> 3, r8 = (fl & 7) * 8;
    u16x8 hv;
    #pragma unroll
    for (int i = 0; i < 8; ++i) hv[i] = f2b(t[r8 + i][c]);
    *(u16x8*)(o + (size_t)c * 512 + r8) = hv;
  }
}

// ---- z_q gather ----
__global__ void k_zq(const u64* __restrict__ keys, const float* __restrict__ emb, float* __restrict__ zq){
  int sidx = blockIdx.x * 64 + threadIdx.x;
  int b = sidx >> 8, s = sidx & 255;
  int v = (int)(u32)keys[sidx];
  const float4* er = (const float4*)(emb + (size_t)v * 512);
  float* o = zq + (size_t)b * 512 * 256 + s;
  #pragma unroll 4
  for (int e4 = 0; e4 < 128; ++e4){
    float4 vv = er[e4];
    o[(size_t)(e4 * 4 + 0) * 256] = vv.x;
    o[(size_t)(e4 * 4 + 1) * 256] = vv.y;
    o[(size_t)(e4 * 4 + 2) * 256] = vv.z;
    o[(size_t)(e4 * 4 + 3) * 256] = vv.w;
  }
}

// ---- small GEMM (proven 128x128 2-phase): GEMM1 & GEMM3 ----
// MODE 0 additionally writes the bf16 TRANSPOSED output (z^T) to ZT
// ([b][s][e] layout) from registers -> the z-transpose kernel is deleted.
template<int MODE>
__global__ __launch_bounds__(256, 4) void k_gemm(
    const u16* __restrict__ Ah,
    const u16* __restrict__ Bh,
    const u64* __restrict__ gkeys,
    const float* __restrict__ bias,
    float* __restrict__ Cout,
    u16* __restrict__ ZT,
    int M, int mtbits)
{
  constexpr int K = 512;
  __shared__ __align__(16) u16 sA[128 * 64];
  __shared__ __align__(16) u16 sB[128 * 64];

  const int tid  = threadIdx.x;
  const int lane = tid & 63;
  const int wid  = tid >> 6;
  const int wm = wid >> 1, wn = wid & 1;

  const int nwg = gridDim.x;
  const int chunk = nwg >> 3;
  const int pb = blockIdx.x;
  const int bid = (pb & 7) * chunk + (pb >> 3);

  const int mt = bid & ((1 << mtbits) - 1);
  const int nt = (bid >> mtbits) & 1;
  const int b  = bid >> (mtbits + 1);
  const int m0 = mt * 128;
  const int n0 = nt * 128;
  const int bbase = b * 256;

  const u16* ga[4];
  const u16* gb[4];
  int ldso[4];
  #pragma unroll
  for (int i = 0; i < 4; ++i){
    int e = i * 256 + tid;
    int r = e >> 3;
    int sl = (e & 7) ^ (r & 7);
    ldso[i] = e * 8;
    ga[i] = Ah + (size_t)(m0 + r) * K + sl * 8;
    size_t brow;
    if (MODE == 2) brow = (size_t)(u32)gkeys[bbase + n0 + r];
    else           brow = (size_t)(bbase + n0 + r);
    gb[i] = Bh + brow * K + sl * 8;
  }

  const f32x4 zero4 = {0.f, 0.f, 0.f, 0.f};
  f32x4 acc[4][4];
  #pragma unroll
  for (int i = 0; i < 4; ++i)
    #pragma unroll
    for (int j = 0; j < 4; ++j) acc[i][j] = zero4;

  int aoff[2][4], boff[2][4];
  #pragma unroll
  for (int ks = 0; ks < 2; ++ks)
    #pragma unroll
    for (int f = 0; f < 4; ++f){
      int rA = wm * 64 + f * 16 + (lane & 15);
      aoff[ks][f] = rA * 64 + (((ks * 4 + (lane >> 4)) ^ (rA & 7)) * 8);
      int rB = wn * 64 + f * 16 + (lane & 15);
      boff[ks][f] = rB * 64 + (((ks * 4 + (lane >> 4)) ^ (rB & 7)) * 8);
    }

  for (int kt = 0; kt < 8; ++kt){
    const int k0 = kt * 64;
    #pragma unroll
    for (int i = 0; i < 4; ++i){
      gload16(&sA[ldso[i]], ga[i] + k0);
      gload16(&sB[ldso[i]], gb[i] + k0);
    }
    __syncthreads();
    #pragma unroll
    for (int ks = 0; ks < 2; ++ks){
      short8 ah[4], bh[4];
      #pragma unroll
      for (int f = 0; f < 4; ++f){
        ah[f] = *(const short8*)&sA[aoff[ks][f]];
        bh[f] = *(const short8*)&sB[boff[ks][f]];
      }
      #pragma unroll
      for (int fm = 0; fm < 4; ++fm)
        #pragma unroll
        for (int fn = 0; fn < 4; ++fn)
          acc[fm][fn] = __builtin_amdgcn_mfma_f32_16x16x32_bf16(ah[fm], bh[fn], acc[fm][fn], 0, 0, 0);
    }
    __syncthreads();
  }

  const int row0 = m0 + wm * 64;
  const int col  = n0 + wn * 64 + (lane & 15);
  float* Cb = Cout + (size_t)b * M * 256;
  #pragma unroll
  for (int fm = 0; fm < 4; ++fm){
    #pragma unroll
    for (int j = 0; j < 4; ++j){
      int row = row0 + fm * 16 + (lane >> 4) * 4 + j;
      float bi = bias[row];
      #pragma unroll
      for (int fn = 0; fn < 4; ++fn)
        Cb[(size_t)row * 256 + col + fn * 16] = acc[fm][fn][j] + bi;
    }
  }

  if (MODE == 0){
    // fused z^T bf16 store: ZT[(b*256 + col)*512 + row], 8B (4-row) chunks
    #pragma unroll
    for (int fm = 0; fm < 4; ++fm){
      int rb4 = row0 + fm * 16 + (lane >> 4) * 4;
      #pragma unroll
      for (int fn = 0; fn < 4; ++fn){
        float bi0 = bias[rb4], bi1 = bias[rb4+1], bi2 = bias[rb4+2], bi3 = bias[rb4+3];
        u16x4 v;
        v[0] = f2b(acc[fm][fn][0] + bi0);
        v[1] = f2b(acc[fm][fn][1] + bi1);
        v[2] = f2b(acc[fm][fn][2] + bi2);
        v[3] = f2b(acc[fm][fn][3] + bi3);
        *(u16x4*)(ZT + (size_t)(bbase + col + fn * 16) * 512 + rb4) = v;
      }
    }
  }
}

// ---- GEMM2: faithful 8-phase m201-style template, fused score+argmin ----
// One block per batch b (256 blocks, 512 thr, 8 waves 2x4, 1 block/CU).
// BM=256 (emb rows per mt), BN=256 (tokens), BK=64. acc[8][4] per wave.
// LDS: 2 tile-buffers x (A 32KB | B 32KB) + cn 16KB = 144KB. slot^row&7
// swizzle (0-conflict, proven). Tile stream tau=0..127 (mt=tau>>3), iteration
// = 2 tiles (tau0 even->buf0, tau1->buf1), 8 phases.
// Per phase: {ds_read quadrant subtile; stage 1 half-tile (2 gloads);
//  [lgkmcnt(8) if 12 reads]; barrier; lgkmcnt(0); setprio1; 16 MFMA;
//  setprio0; barrier}.  vmcnt(6) ONLY at phases 4 and 8 (before the barrier).
// Stage map (iter j, t0=2j,t1=2j+1): ph1->B(t1)H, ph2->A(t0+2)L, ph3->B(t0+2)L,
//  ph4->A(t0+2)H, ph5->B(t0+2)H, ph6->A(t1+2)L, ph7->B(t1+2)L, ph8->A(t1+2)H.
// Derivation: vmcnt(6)@ph4 confirms everything through ph1's stage (needed by
// ph5/ph6/ph7); vmcnt(6)@ph8 confirms through ph5 (needed by next ph1/ph2/ph3).
// Write-safety: every stage dest's last read completed before that phase's
// gload issue (reads drain at lgkmcnt(0) before the preceding barrier).
// Tail: stage sources wrap (tp&127), data never read. Accumulation order per
// acc element identical to rounds 2-5 -> bit-identical tokens.
__global__ __launch_bounds__(512, 1) void k_gemm2(
    const u16* __restrict__ Ah,      // emb_b [4096][512]
    const u16* __restrict__ Bh,      // zb [65536][512]
    const float* __restrict__ cnorm,
    u64* __restrict__ okeys)
{
  __shared__ __align__(16) u16 lds[73728];  // buf0 32K u16 | buf1 32K u16 | cn 8K u16

  const int tid  = threadIdx.x;
  const int lane = tid & 63;
  const int wid  = tid >> 6;
  const int wm   = wid >> 2;
  const int wn   = wid & 3;
  const int b    = blockIdx.x;
  const int bbase = b * 256;

  float* cn = (float*)&lds[65536];
  {
    const float4* c4 = (const float4*)cnorm;
    ((float4*)cn)[tid] = c4[tid];
    ((float4*)cn)[tid + 512] = c4[tid + 512];
  }
  __syncthreads();

  // staging geometry (LDS[r][s] = G[r][s ^ (r&7)], 16B slots)
  const int l8 = lane >> 3;
  const int sl = (lane & 7) ^ l8;
  const int arb = (wid < 4) ? wid * 16 : 128 + (wid - 4) * 16;   // A-L rows {0-63,128-191}
  const int brb = (wid >> 1) * 64 + (wid & 1) * 16;              // B-L rows {0-31,64-95,...}
  const size_t aS = (size_t)(arb + l8) * 512 + sl * 8;
  const size_t bS = (size_t)(bbase + brb + l8) * 512 + sl * 8;
  const int dAL = arb * 64 + lane * 8;            // + buf*32768 ; A-H: +4096
  const int dBL = 16384 + brb * 64 + lane * 8;    // + buf*32768 ; B-H: +2048

#define STG2(doff, sp) { gload16(&lds[doff], (sp)); gload16(&lds[(doff) + 512], (sp) + 4096); }
#define SRC_AL(tp) (Ah + aS + (size_t)(((tp) & 127) >> 3) * 131072 + ((tp) & 7) * 64)
#define SRC_AH(tp) (SRC_AL(tp) + 32768)
#define SRC_BL(tp) (Bh + bS + ((tp) & 7) * 64)
#define SRC_BH(tp) (SRC_BL(tp) + 16384)

#define SB   __builtin_amdgcn_sched_barrier(0)
#define BAR  __builtin_amdgcn_s_barrier()
#define LGKM8 asm volatile("s_waitcnt lgkmcnt(8)" ::: "memory")
#define LGKM0 asm volatile("s_waitcnt lgkmcnt(0)" ::: "memory")
#define VM6  asm volatile("s_waitcnt vmcnt(6)" ::: "memory")
#define VM0  asm volatile("s_waitcnt vmcnt(0)" ::: "memory")

  // ds_read fragment bases (rA&7 == lane&7 for all f)
  const int aof0 = (wm * 128 + (lane & 15)) * 64 + (((lane >> 4)    ) ^ (lane & 7)) * 8;
  const int aof1 = (wm * 128 + (lane & 15)) * 64 + ((4 + (lane >> 4)) ^ (lane & 7)) * 8;
  const int bof0 = 16384 + (wn * 64 + (lane & 15)) * 64 + (((lane >> 4)    ) ^ (lane & 7)) * 8;
  const int bof1 = 16384 + (wn * 64 + (lane & 15)) * 64 + ((4 + (lane >> 4)) ^ (lane & 7)) * 8;

#define RD_AL(cb) { _Pragma("unroll") for (int f = 0; f < 4; ++f){ \
    ah[f][0] = *(const short8*)&lds[(cb) + aof0 + f * 1024]; \
    ah[f][1] = *(const short8*)&lds[(cb) + aof1 + f * 1024]; } }
#define RD_AH(cb) { _Pragma("unroll") for (int f = 0; f < 4; ++f){ \
    ah[f][0] = *(const short8*)&lds[(cb) + aof0 + 4096 + f * 1024]; \
    ah[f][1] = *(const short8*)&lds[(cb) + aof1 + 4096 + f * 1024]; } }
#define RD_BL(cb) { _Pragma("unroll") for (int f = 0; f < 2; ++f){ \
    bhL[f][0] = *(const short8*)&lds[(cb) + bof0 + f * 1024]; \
    bhL[f][1] = *(const short8*)&lds[(cb) + bof1 + f * 1024]; } }
#define RD_BH(cb) { _Pragma("unroll") for (int f = 0; f < 2; ++f){ \
    bhH[f][0] = *(const short8*)&lds[(cb) + bof0 + 2048 + f * 1024]; \
    bhH[f][1] = *(const short8*)&lds[(cb) + bof1 + 2048 + f * 1024]; } }

#define MMQ(MB, NB, BV) { __builtin_amdgcn_s_setprio(1); \
  _Pragma("unroll") for (int ks = 0; ks < 2; ++ks) \
    _Pragma("unroll") for (int fm = 0; fm < 4; ++fm) \
      _Pragma("unroll") for (int fn = 0; fn < 2; ++fn) \
        acc[(MB) + fm][(NB) + fn] = __builtin_amdgcn_mfma_f32_16x16x32_bf16( \
            ah[fm][ks], BV[fn][ks], acc[(MB) + fm][(NB) + fn], 0, 0, 0); \
  __builtin_amdgcn_s_setprio(0); SB; BAR; }

  const f32x4 zero4 = {0.f, 0.f, 0.f, 0.f};
  f32x4 acc[8][4];
  #pragma unroll
  for (int i = 0; i < 8; ++i)
    #pragma unroll
    for (int j = 0; j < 4; ++j) acc[i][j] = zero4;

  u64 best[4];
  #pragma unroll
  for (int i = 0; i < 4; ++i) best[i] = ~0ull;

  short8 ah[4][2], bhL[2][2], bhH[2][2];

  // prologue: tiles 0 (full) + 1 (all but B1H, which iter0-ph1 stages)
  STG2(dAL,                 SRC_AL(0)) STG2(dBL,         SRC_BL(0))
  STG2(dBL + 2048,          SRC_BH(0)) STG2(dAL + 4096,  SRC_AH(0))
  STG2(32768 + dAL,         SRC_AL(1)) STG2(32768 + dBL, SRC_BL(1))
  STG2(32768 + dAL + 4096,  SRC_AH(1))
  VM0; BAR; SB;

  #pragma unroll 1
  for (int j = 0; j < 64; ++j){
    const int t0 = 2 * j, t1 = 2 * j + 1;

    // ph1: Q00(buf0); stage B(t1)H
    RD_AL(0) RD_BL(0)
    STG2(32768 + dBL + 2048, SRC_BH(t1))
    LGKM8; SB; BAR; LGKM0; SB;
    MMQ(0, 0, bhL)
    // ph2: Q01(buf0); stage A(t0+2)L
    RD_BH(0)
    STG2(dAL, SRC_AL(t0 + 2))
    SB; BAR; LGKM0; SB;
    MMQ(0, 2, bhH)
    // ph3: Q11(buf0); stage B(t0+2)L
    RD_AH(0)
    STG2(dBL, SRC_BL(t0 + 2))
    SB; BAR; LGKM0; SB;
    MMQ(4, 2, bhH)
    // ph4: Q10(buf0); stage A(t0+2)H; vmcnt(6)
    STG2(dAL + 4096, SRC_AH(t0 + 2))
    VM6; SB; BAR; SB;
    MMQ(4, 0, bhL)
    // ph5: Q00(buf1); stage B(t0+2)H
    RD_AL(32768) RD_BL(32768)
    STG2(dBL + 2048, SRC_BH(t0 + 2))
    LGKM8; SB; BAR; LGKM0; SB;
    MMQ(0, 0, bhL)
    // ph6: Q01(buf1); stage A(t1+2)L
    RD_BH(32768)
    STG2(32768 + dAL, SRC_AL(t1 + 2))
    SB; BAR; LGKM0; SB;
    MMQ(0, 2, bhH)
    // ph7: Q11(buf1); stage B(t1+2)L
    RD_AH(32768)
    STG2(32768 + dBL, SRC_BL(t1 + 2))
    SB; BAR; LGKM0; SB;
    MMQ(4, 2, bhH)
    // ph8: Q10(buf1); stage A(t1+2)H; vmcnt(6)
    STG2(32768 + dAL + 4096, SRC_AH(t1 + 2))
    VM6; SB; BAR; SB;
    MMQ(4, 0, bhL)

    if ((j & 3) == 3){
      const int mt = j >> 2;
      #pragma unroll
      for (int fn = 0; fn < 4; ++fn){
        #pragma unroll
        for (int fm = 0; fm < 8; ++fm){
          #pragma unroll
          for (int jj = 0; jj < 4; ++jj){
            int v = mt * 256 + wm * 128 + fm * 16 + (lane >> 4) * 4 + jj;
            float sc = cn[v] - 2.0f * acc[fm][fn][jj];
            u32 o = __float_as_uint(sc);
            o = (o & 0x80000000u) ? ~o : (o | 0x80000000u);
            best[fn] = umin64(best[fn], ((u64)o << 32) | (u32)v);
          }
        }
      }
      #pragma unroll
      for (int i = 0; i < 8; ++i)
        #pragma unroll
        for (int jj = 0; jj < 4; ++jj) acc[i][jj] = zero4;
    }
  }

  // block reduce + single store (no atomics)
  #pragma unroll
  for (int fn = 0; fn < 4; ++fn){
    best[fn] = umin64(best[fn], shfl_xor_u64(best[fn], 16));
    best[fn] = umin64(best[fn], shfl_xor_u64(best[fn], 32));
  }
  VM0;
  __syncthreads();
  u64* kbuf = (u64*)&lds[0];
  if (lane < 16){
    #pragma unroll
    for (int fn = 0; fn < 4; ++fn)
      kbuf[wm * 256 + wn * 64 + fn * 16 + lane] = best[fn];
  }
  __syncthreads();
  if (tid < 256)
    okeys[bbase + tid] = umin64(kbuf[tid], kbuf[256 + tid]);

#undef STG2
#undef SRC_AL
#undef SRC_AH
#undef SRC_BL
#undef SRC_BH
#undef SB
#undef BAR
#undef LGKM8
#undef LGKM0
#undef VM6
#undef VM0
#undef RD_AL
#undef RD_AH
#undef RD_BL
#undef RD_BH
#undef MMQ
}

extern "C" void kernel_launch(void* const* d_in, const int* in_sizes, int n_in,
                              void* d_out, int out_size, void* d_ws, size_t ws_size,
                              hipStream_t stream){
  const float* x      = (const float*)d_in[0];
  const float* pre_w  = (const float*)d_in[1];
  const float* pre_b  = (const float*)d_in[2];
  const float* emb    = (const float*)d_in[3];
  const float* post_w = (const float*)d_in[4];
  const float* post_b = (const float*)d_in[5];

  float* z_out   = (float*)d_out;              // [256][512][256]
  float* zq_out  = z_out + 33554432;           // [256][512][256]
  float* rec_out = z_out + 67108864;           // [256][512][256]

  char* w = (char*)d_ws;
  u16* prew_b  = (u16*)(w);                    // 512KB
  u16* postw_b = (u16*)(w + 524288);           // 512KB
  u16* emb_b   = (u16*)(w + 1048576);          // 4MB
  float* cnorm = (float*)(w + 5242880);        // 16KB
  u64* keys    = (u64*)(w + 5259264);          // 512KB
  u16* xb      = (u16*)(w + 5783552);          // 64MB [65536][512] bf16 (x^T)
  u16* zb      = (u16*)(w + 72892416);         // 64MB [65536][512] bf16 (z^T, own region)

  k_cvt  <<<1024, 256, 0, stream>>>(pre_w, prew_b, 262144);
  k_cvt  <<<1024, 256, 0, stream>>>(post_w, postw_b, 262144);
  k_cvt  <<<8192, 256, 0, stream>>>(emb, emb_b, 2097152);
  k_cnorm<<<4096, 64, 0, stream>>>(emb, cnorm);

  // x [b][c][s] -> xb [b][s][c]
  k_tcvt<<<8192, 256, 0, stream>>>(x, xb);

  // GEMM1: z = pre_w * x + pre_b ; fused z^T bf16 -> zb (kills 2nd transpose)
  k_gemm<0><<<256 * 2 * 4, 256, 0, stream>>>(prew_b, xb,
      nullptr, pre_b, z_out, zb, 512, 2);

  // GEMM2: 8-phase template scores + fused argmin -> keys
  k_gemm2<<<256, 512, 0, stream>>>(emb_b, zb, cnorm, keys);

  // z_q gather (exact f32)
  k_zq<<<1024, 64, 0, stream>>>(keys, emb, zq_out);

  // GEMM3: rec = post_w * z_q + post_b  (B staged by gathering emb_b rows via tokens)
  k_gemm<2><<<256 * 2 * 4, 256, 0, stream>>>(postw_b, emb_b,
      keys, post_b, rec_out, nullptr, 512, 2);
}